// Round 1
// baseline (1002.941 us; speedup 1.0000x reference)
//
#include <hip/hip_runtime.h>
#include <math.h>

#define NN 50000
#define EE 400000
#define ETOT 450000      // EE + NN self loops
#define CC 64
#define HH 4
#define DEA 16
#define NBATCH 64
#define HC 256           // HH*CC
#define EPSV 1e-5f

__device__ __forceinline__ float4 ld4(const float* p){ return *(const float4*)p; }

// ---------- edge_attr column sums (for self-loop mean fill) ----------
__global__ void k_easum(const float* __restrict__ ea, float* __restrict__ easum){
  int tid = threadIdx.x;
  int gid = blockIdx.x*256 + tid;
  int gsz = gridDim.x*256;              // 262144, multiple of 16 -> col stable
  float s = 0.f;
  for (long long i = gid; i < (long long)EE*DEA; i += gsz) s += ea[i];
  __shared__ float sd[256];
  sd[tid] = s; __syncthreads();
  if (tid < DEA){
    float t = 0.f;
    for (int j = tid; j < 256; j += DEA) t += sd[j];
    atomicAdd(&easum[tid], t);
  }
}

// ---------- CSR build ----------
__global__ void k_hist(const int* __restrict__ dst, int* __restrict__ cnt){
  int e = blockIdx.x*256 + threadIdx.x;
  if (e < ETOT){
    int d = (e < EE) ? dst[e] : (e - EE);
    atomicAdd(&cnt[d], 1);
  }
}

__global__ void k_scan(int* __restrict__ data, int* __restrict__ row_ptr, int n){
  __shared__ int wsum[16];
  __shared__ int carry_s;
  int tid = threadIdx.x;               // blockDim = 1024
  int lane = tid & 63, wv = tid >> 6;
  if (tid == 0) carry_s = 0;
  __syncthreads();
  for (int base = 0; base < n; base += 1024){
    int i = base + tid;
    int v = (i < n) ? data[i] : 0;
    int incl = v;
    #pragma unroll
    for (int off = 1; off < 64; off <<= 1){
      int t = __shfl_up(incl, off, 64);
      if (lane >= off) incl += t;
    }
    if (lane == 63) wsum[wv] = incl;
    __syncthreads();
    if (wv == 0){
      int s = (lane < 16) ? wsum[lane] : 0;
      #pragma unroll
      for (int off = 1; off < 16; off <<= 1){
        int t = __shfl_up(s, off, 64);
        if (lane >= off) s += t;
      }
      if (lane < 16) wsum[lane] = s;
    }
    __syncthreads();
    int woff = (wv > 0) ? wsum[wv-1] : 0;
    int excl = carry_s + woff + incl - v;
    if (i < n){ row_ptr[i] = excl; data[i] = excl; }
    __syncthreads();
    if (tid == 0) carry_s += wsum[15];
    __syncthreads();
  }
  if (tid == 0) row_ptr[n] = carry_s;
}

__global__ void k_scatter(const int* __restrict__ dst, int* __restrict__ wp, int* __restrict__ col){
  int e = blockIdx.x*256 + threadIdx.x;
  if (e < ETOT){
    int d = (e < EE) ? dst[e] : (e - EE);
    int pos = atomicAdd(&wp[d], 1);
    col[pos] = e;
  }
}

// ---------- GraphNorm + ReLU (one block per batch segment; batch is sorted) ----------
__device__ __forceinline__ int lowerb(const int* a, int n, int key){
  int lo = 0, hi = n;
  while (lo < hi){ int mid = (lo+hi) >> 1; if (a[mid] < key) lo = mid+1; else hi = mid; }
  return lo;
}

__global__ __launch_bounds__(256)
void k_norm(const float* __restrict__ x, const int* __restrict__ batch,
            const float* __restrict__ w, const float* __restrict__ b,
            const float* __restrict__ ms, float* __restrict__ h){
  __shared__ int sb[2];
  __shared__ float red[4][64];
  __shared__ float stat[64];
  int tid = threadIdx.x;
  int bb = blockIdx.x;
  if (tid == 0){ sb[0] = lowerb(batch, NN, bb); sb[1] = lowerb(batch, NN, bb+1); }
  __syncthreads();
  int lo = sb[0], hi = sb[1];
  float inv = 1.0f / fmaxf((float)(hi - lo), 1.0f);
  int c = tid & 63, g = tid >> 6;
  float msv = ms[c];
  float ps = 0.f;
  for (int n = lo+g; n < hi; n += 4) ps += x[(size_t)n*CC + c];
  red[g][c] = ps; __syncthreads();
  if (g == 0) stat[c] = (red[0][c]+red[1][c]+red[2][c]+red[3][c]) * inv;
  __syncthreads();
  float mean = stat[c];
  float pv = 0.f;
  for (int n = lo+g; n < hi; n += 4){ float s = x[(size_t)n*CC+c] - msv*mean; pv += s*s; }
  red[g][c] = pv; __syncthreads();
  if (g == 0) stat[c] = rsqrtf((red[0][c]+red[1][c]+red[2][c]+red[3][c])*inv + EPSV);
  __syncthreads();
  float rstd = stat[c];
  float wv = w[c], bv = b[c];
  for (int n = lo+g; n < hi; n += 4){
    float s = x[(size_t)n*CC+c] - msv*mean;
    float v = s*rstd*wv + bv;
    h[(size_t)n*CC+c] = fmaxf(v, 0.f);
  }
}

// ---------- GEMM: [N,64] @ [64,256] -> [N,256], two weight matrices via blockIdx.z ----------
__global__ __launch_bounds__(256)
void k_gemm(const float* __restrict__ h, const float* __restrict__ WA, const float* __restrict__ WB,
            float* __restrict__ outA, float* __restrict__ outB){
  const float* W = blockIdx.z ? WB : WA;
  float* out = blockIdx.z ? outB : outA;
  int n0 = blockIdx.x * 32;
  int c0 = blockIdx.y * 128;
  __shared__ float hT[64][40];     // transposed h tile, stride 40 (16B-aligned rows)
  __shared__ float Ws[64][128];
  int tid = threadIdx.x;
  for (int t = tid; t < 512; t += 256){
    int r = t >> 4, ch = t & 15;
    int n = n0 + r;
    float4 v = (n < NN) ? ld4(h + (size_t)n*CC + ch*4) : make_float4(0.f,0.f,0.f,0.f);
    hT[ch*4+0][r] = v.x; hT[ch*4+1][r] = v.y; hT[ch*4+2][r] = v.z; hT[ch*4+3][r] = v.w;
  }
  for (int t = tid; t < 2048; t += 256){
    int k = t >> 5, ch = t & 31;
    float4 v = ld4(W + (size_t)k*HC + c0 + ch*4);
    *(float4*)&Ws[k][ch*4] = v;
  }
  __syncthreads();
  int rIdx = tid >> 5, cIdx = tid & 31;
  int r0 = rIdx*4, cc0 = cIdx*4;
  float acc[4][4] = {{0.f}};
  #pragma unroll 8
  for (int k = 0; k < 64; k++){
    float4 a = *(const float4*)&hT[k][r0];
    float4 bq = *(const float4*)&Ws[k][cc0];
    acc[0][0] += a.x*bq.x; acc[0][1] += a.x*bq.y; acc[0][2] += a.x*bq.z; acc[0][3] += a.x*bq.w;
    acc[1][0] += a.y*bq.x; acc[1][1] += a.y*bq.y; acc[1][2] += a.y*bq.z; acc[1][3] += a.y*bq.w;
    acc[2][0] += a.z*bq.x; acc[2][1] += a.z*bq.y; acc[2][2] += a.z*bq.z; acc[2][3] += a.z*bq.w;
    acc[3][0] += a.w*bq.x; acc[3][1] += a.w*bq.y; acc[3][2] += a.w*bq.z; acc[3][3] += a.w*bq.w;
  }
  #pragma unroll
  for (int i = 0; i < 4; i++){
    int n = n0 + r0 + i;
    if (n < NN){
      float4 o = make_float4(acc[i][0], acc[i][1], acc[i][2], acc[i][3]);
      *(float4*)(out + (size_t)n*HC + c0 + cc0) = o;
    }
  }
}

// ---------- per-edge logits: wave per edge, We in registers ----------
__global__ __launch_bounds__(256)
void k_logits(const float* __restrict__ xl, const float* __restrict__ xr,
              const int* __restrict__ src, const int* __restrict__ dst,
              const float* __restrict__ ea, const float* __restrict__ easum,
              const float* __restrict__ We, const float* __restrict__ att,
              float* __restrict__ lgout){
  int lane = threadIdx.x & 63;
  int gwid = (blockIdx.x*256 + threadIdx.x) >> 6;
  int nw = (gridDim.x*256) >> 6;
  float wer[4][16];
  #pragma unroll
  for (int j = 0; j < 4; j++)
    #pragma unroll
    for (int k = 0; k < 16; k++)
      wer[j][k] = We[(size_t)k*HC + j*64 + lane];
  float attv[4];
  #pragma unroll
  for (int j = 0; j < 4; j++) attv[j] = att[j*64 + lane];
  float ems[16];
  const float invE = 1.0f / (float)EE;
  #pragma unroll
  for (int k = 0; k < 16; k++) ems[k] = easum[k] * invE;

  for (int e = gwid; e < ETOT; e += nw){
    int s, d;
    float ear[16];
    if (e < EE){
      s = src[e]; d = dst[e];
      #pragma unroll
      for (int q = 0; q < 4; q++){
        float4 v = ld4(ea + (size_t)e*DEA + q*4);
        ear[q*4+0]=v.x; ear[q*4+1]=v.y; ear[q*4+2]=v.z; ear[q*4+3]=v.w;
      }
    } else {
      s = e - EE; d = s;
      #pragma unroll
      for (int k = 0; k < 16; k++) ear[k] = ems[k];
    }
    const float* xls = xl + (size_t)s*HC;
    const float* xrd = xr + (size_t)d*HC;
    float p[4];
    #pragma unroll
    for (int j = 0; j < 4; j++){
      int col = j*64 + lane;
      float eev = 0.f;
      #pragma unroll
      for (int k = 0; k < 16; k++) eev += ear[k]*wer[j][k];
      float v = xls[col] + xrd[col] + eev;
      v = (v > 0.f) ? v : 0.2f*v;
      p[j] = v * attv[j];
    }
    #pragma unroll
    for (int off = 32; off > 0; off >>= 1){
      p[0] += __shfl_xor(p[0], off, 64);
      p[1] += __shfl_xor(p[1], off, 64);
      p[2] += __shfl_xor(p[2], off, 64);
      p[3] += __shfl_xor(p[3], off, 64);
    }
    if (lane == 0){
      float4 o = make_float4(p[0], p[1], p[2], p[3]);
      *(float4*)(lgout + (size_t)e*4) = o;
    }
  }
}

// ---------- per-node softmax + aggregation: wave per node (CSR, no atomics) ----------
__global__ __launch_bounds__(256)
void k_aggr(const int* __restrict__ row_ptr, const int* __restrict__ col,
            const int* __restrict__ src, const float* __restrict__ lg,
            const float* __restrict__ xl, const float* __restrict__ bias,
            const float* __restrict__ resid, float* __restrict__ out){
  int lane = threadIdx.x & 63;
  int n = blockIdx.x*4 + (threadIdx.x >> 6);
  if (n >= NN) return;
  int rr0 = row_ptr[n], rr1 = row_ptr[n+1];
  float m0=-3.4e38f, m1=m0, m2=m0, m3=m0;
  for (int idx = rr0 + lane; idx < rr1; idx += 64){
    int e = col[idx];
    float4 l = ld4(lg + (size_t)e*4);
    m0 = fmaxf(m0, l.x); m1 = fmaxf(m1, l.y); m2 = fmaxf(m2, l.z); m3 = fmaxf(m3, l.w);
  }
  #pragma unroll
  for (int off = 32; off > 0; off >>= 1){
    m0 = fmaxf(m0, __shfl_xor(m0, off, 64));
    m1 = fmaxf(m1, __shfl_xor(m1, off, 64));
    m2 = fmaxf(m2, __shfl_xor(m2, off, 64));
    m3 = fmaxf(m3, __shfl_xor(m3, off, 64));
  }
  float d0=0.f, d1=0.f, d2=0.f, d3=0.f;
  for (int idx = rr0 + lane; idx < rr1; idx += 64){
    int e = col[idx];
    float4 l = ld4(lg + (size_t)e*4);
    d0 += __expf(l.x - m0); d1 += __expf(l.y - m1);
    d2 += __expf(l.z - m2); d3 += __expf(l.w - m3);
  }
  #pragma unroll
  for (int off = 32; off > 0; off >>= 1){
    d0 += __shfl_xor(d0, off, 64); d1 += __shfl_xor(d1, off, 64);
    d2 += __shfl_xor(d2, off, 64); d3 += __shfl_xor(d3, off, 64);
  }
  float i0 = 1.0f/d0, i1 = 1.0f/d1, i2 = 1.0f/d2, i3 = 1.0f/d3;
  float acc = 0.f;
  for (int idx = rr0; idx < rr1; idx++){
    int e = col[idx];
    int s = (e < EE) ? src[e] : (e - EE);
    float4 l = ld4(lg + (size_t)e*4);
    float a0 = __expf(l.x - m0)*i0;
    float a1 = __expf(l.y - m1)*i1;
    float a2 = __expf(l.z - m2)*i2;
    float a3 = __expf(l.w - m3)*i3;
    const float* xs = xl + (size_t)s*HC + lane;
    acc += a0*xs[0] + a1*xs[64] + a2*xs[128] + a3*xs[192];
  }
  float val = acc*0.25f + bias[lane];
  if (resid) val += resid[(size_t)n*CC + lane];
  out[(size_t)n*CC + lane] = val;
}

extern "C" void kernel_launch(void* const* d_in, const int* in_sizes, int n_in,
                              void* d_out, int out_size, void* d_ws, size_t ws_size,
                              hipStream_t stream) {
  const float* x     = (const float*)d_in[0];
  const int*   ei    = (const int*)d_in[1];
  const int*   src   = ei;
  const int*   dst   = ei + EE;
  const float* ea    = (const float*)d_in[2];
  const int*   batch = (const int*)d_in[3];
  const float* Wl    = (const float*)d_in[4];
  const float* Wr    = (const float*)d_in[5];
  const float* We    = (const float*)d_in[6];
  const float* att   = (const float*)d_in[7];
  const float* gb    = (const float*)d_in[8];
  const float* gw    = (const float*)d_in[9];
  const float* gnb   = (const float*)d_in[10];
  const float* gms   = (const float*)d_in[11];
  float* out = (float*)d_out;

  char* ws = (char*)d_ws;
  size_t off = 0;
  auto alloc = [&](size_t bytes) -> void* {
    void* p = ws + off; off += (bytes + 255) & ~(size_t)255; return p;
  };
  int*   row_ptr = (int*)alloc((NN+1)*sizeof(int));
  int*   wp      = (int*)alloc(NN*sizeof(int));
  int*   colA    = (int*)alloc((size_t)ETOT*sizeof(int));
  float* easum   = (float*)alloc(64);
  float* hbuf    = (float*)alloc((size_t)NN*CC*sizeof(float));
  float* xl      = (float*)alloc((size_t)NN*HC*sizeof(float));
  float* xr      = (float*)alloc((size_t)NN*HC*sizeof(float));
  float* lgbuf   = (float*)alloc((size_t)ETOT*HH*sizeof(float));
  float* xbuf    = (float*)alloc((size_t)NN*CC*sizeof(float));
  if (off > ws_size) return;   // insufficient workspace -> fail loudly (no launch)

  hipMemsetAsync(wp, 0, NN*sizeof(int), stream);
  hipMemsetAsync(easum, 0, 64, stream);
  k_easum<<<1024, 256, 0, stream>>>(ea, easum);
  k_hist<<<(ETOT+255)/256, 256, 0, stream>>>(dst, wp);
  k_scan<<<1, 1024, 0, stream>>>(wp, row_ptr, NN);
  k_scatter<<<(ETOT+255)/256, 256, 0, stream>>>(dst, wp, colA);

  for (int i = 0; i < 2; i++){
    const float* xin = i ? xbuf : x;
    k_norm<<<NBATCH, 256, 0, stream>>>(xin, batch, gw + i*CC, gnb + i*CC, gms + i*CC, hbuf);
    k_gemm<<<dim3((NN+31)/32, 2, 2), 256, 0, stream>>>(hbuf, Wl + (size_t)i*CC*HC, Wr + (size_t)i*CC*HC, xl, xr);
    k_logits<<<2048, 256, 0, stream>>>(xl, xr, src, dst, ea, easum,
                                       We + (size_t)i*DEA*HC, att + i*HH*CC, lgbuf);
    k_aggr<<<(NN+3)/4, 256, 0, stream>>>(row_ptr, colA, src, lgbuf, xl, gb + i*CC,
                                         i ? x : nullptr, i ? out : xbuf);
  }
}